// Round 21
// baseline (500.444 us; speedup 1.0000x reference)
//
// ViT block on MI355X — round 24: proj & fc2 (N=768, grid 192@256^2 = 25% CUs
// idle, 1 blk/CU) moved to the PROVEN round-0..5 128^2 m97-style kernel
// (16KB LDS, 256thr -> grid 768, ~3 blk/CU co-resident). QKV/fc1 stay 256^2.
// 128^2 epilogues ported to bf16 residual chain. Rest identical to r19 (491.3).
#include <hip/hip_runtime.h>
#include <hip/hip_bf16.h>
#include <math.h>

typedef unsigned short u16;
typedef unsigned int u32;
typedef float f32x4 __attribute__((ext_vector_type(4)));
typedef short bf16x8 __attribute__((ext_vector_type(8)));
typedef unsigned short us4 __attribute__((ext_vector_type(4)));
typedef int i32x4 __attribute__((ext_vector_type(4)));

struct alignas(16) F4 { float v[4]; };
template <int N> struct Tag { static constexpr int v = N; };

static constexpr int Bb = 16;
static constexpr int Cc = 768;
static constexpr int Nn = 1024;
static constexpr int NH = 12;
static constexpr int HD = 64;
static constexpr float LOG2E = 1.4426950408889634f;

static __device__ __forceinline__ u16 f2bf(float f) {
  union { float f; unsigned u; } v; v.f = f;
  unsigned u = v.u;
  u += 0x7fffu + ((u >> 16) & 1u);
  return (u16)(u >> 16);
}
static __device__ __forceinline__ float bf2f(u16 x) {
  union { unsigned u; float f; } v; v.u = ((unsigned)x) << 16; return v.f;
}
static __device__ __forceinline__ void gload16(const u16* g, u16* l) {
  __builtin_amdgcn_global_load_lds((const __attribute__((address_space(1))) u32*)g,
                                   (__attribute__((address_space(3))) u32*)l, 16, 0, 0);
}
// exact-GELU via A&S 7.1.26 erf (max abs err 1.5e-7 < bf16 ulp of output)
static __device__ __forceinline__ float gelu_f(float v) {
  float z = v * 0.70710678118654752f;
  float az = fabsf(z);
  float t = __builtin_amdgcn_rcpf(1.f + 0.3275911f * az);
  float poly = t * (0.254829592f + t * (-0.284496736f + t * (1.421413741f +
               t * (-1.453152027f + t * 1.061405429f))));
  float e = __builtin_amdgcn_exp2f(-az * az * LOG2E);
  float erfv = 1.f - poly * e;
  erfv = (z < 0.f) ? -erfv : erfv;
  return 0.5f * v * (1.f + erfv);
}
static __device__ __forceinline__ us4 pack4(const float* s) {
  us4 r;
  r[0] = f2bf(s[0]); r[1] = f2bf(s[1]); r[2] = f2bf(s[2]); r[3] = f2bf(s[3]);
  return r;
}

// ---- merged prep (x4 vectorized): weight/bias conversion + x transpose (bf16)
// + attn-bias table. blocks [0,6913): prep4; [6913,19201): transpose;
// [19201,31489): bias_pre4.
__global__ __launch_bounds__(256) void k_pre_all(const float* __restrict__ q_w,
    const float* __restrict__ kv_w, const float* __restrict__ proj_w,
    const float* __restrict__ fc1_w, const float* __restrict__ fc2_w,
    const float* __restrict__ q_b, const float* __restrict__ kv_b,
    u16* __restrict__ wqkv, u16* __restrict__ wproj, u16* __restrict__ wfc1,
    u16* __restrict__ wfc2, float* __restrict__ bqkv,
    const float* __restrict__ x, u16* __restrict__ xt,
    const float* __restrict__ rpb, const int* __restrict__ rel,
    u16* __restrict__ bias2) {
  const int bid = blockIdx.x, tid = threadIdx.x;
  if (bid < 6913) {
    int i4 = bid * 256 + tid;
    if (i4 >= 1769664) return;
    int i = i4 * 4;                       // all segment bounds are %4 == 0
    if (i < 589824) {
      f32x4 sv = *(const f32x4*)&q_w[i];
      *(us4*)&wqkv[i] = pack4((const float*)&sv);
    } else if (i < 1769472) {
      f32x4 sv = *(const f32x4*)&kv_w[i - 589824];
      *(us4*)&wqkv[i] = pack4((const float*)&sv);
    } else if (i < 2359296) {
      f32x4 sv = *(const f32x4*)&proj_w[i - 1769472];
      *(us4*)&wproj[i - 1769472] = pack4((const float*)&sv);
    } else if (i < 4718592) {
      f32x4 sv = *(const f32x4*)&fc1_w[i - 2359296];
      *(us4*)&wfc1[i - 2359296] = pack4((const float*)&sv);
    } else if (i < 7077888) {
      f32x4 sv = *(const f32x4*)&fc2_w[i - 4718592];
      *(us4*)&wfc2[i - 4718592] = pack4((const float*)&sv);
    } else if (i < 7078656) {
      f32x4 sv;
      if (i - 7077888 < 768) sv = *(const f32x4*)&q_b[i - 7077888];
      else                   sv = *(const f32x4*)&kv_b[i - 7078656];
      *(f32x4*)&bqkv[i - 7077888] = sv;
    } else {
      f32x4 sv = *(const f32x4*)&kv_b[i - 7078656];
      *(f32x4*)&bqkv[i - 7077888] = sv;
    }
  } else if (bid < 19201) {
    __shared__ float tile[32][33];
    int j = bid - 6913;
    int n0 = (j & 31) * 32, c0 = ((j >> 5) % 24) * 32, b = j / 768;
    int tx = tid & 31, ty = tid >> 5;   // 32 x 8
    const float* xp = x + (size_t)b * Cc * Nn;
    #pragma unroll
    for (int i = 0; i < 32; i += 8)
      tile[ty + i][tx] = xp[(size_t)(c0 + ty + i) * Nn + n0 + tx];
    __syncthreads();
    u16* xtp = xt + (size_t)b * Nn * Cc;
    #pragma unroll
    for (int i = 0; i < 32; i += 8)
      xtp[(size_t)(n0 + ty + i) * Cc + c0 + tx] = f2bf(tile[tx][ty + i]);
  } else {
    // bias_pre x4: idx over h(12) x q(1024) x kg(256); k = kg*4
    int idx = (bid - 19201) * 256 + tid;
    int kg = idx & 255, q = (idx >> 8) & 1023, h = idx >> 18;
    int k = kg * 4;
    i32x4 rv = *(const i32x4*)&rel[(size_t)q * Nn + k];
    us4 ov;
    ov[0] = f2bf(rpb[rv[0] * NH + h] * LOG2E);
    ov[1] = f2bf(rpb[rv[1] * NH + h] * LOG2E);
    ov[2] = f2bf(rpb[rv[2] * NH + h] * LOG2E);
    ov[3] = f2bf(rpb[rv[3] * NH + h] * LOG2E);
    *(us4*)&bias2[((size_t)h * Nn + q) * Nn + k] = ov;
  }
}

// LayerNorm rows of 768: bf16 in -> bf16 out. One wave/row, 4 rows/block.
__global__ __launch_bounds__(256) void k_layernorm(const u16* __restrict__ in,
    const float* __restrict__ gam, const float* __restrict__ bet,
    u16* __restrict__ out) {
  int wave = threadIdx.x >> 6, lane = threadIdx.x & 63;
  int row = blockIdx.x * 4 + wave;
  const u16* p = in + (size_t)row * Cc;
  float v[12]; float s = 0.f;
  #pragma unroll
  for (int i = 0; i < 6; i++) {
    u32 pr = *(const u32*)&p[2 * (lane + i * 64)];
    v[2 * i]     = bf2f((u16)(pr & 0xffff));
    v[2 * i + 1] = bf2f((u16)(pr >> 16));
    s += v[2 * i] + v[2 * i + 1];
  }
  #pragma unroll
  for (int m = 32; m >= 1; m >>= 1) s += __shfl_xor(s, m);
  float mean = s * (1.f / 768.f);
  float q = 0.f;
  #pragma unroll
  for (int i = 0; i < 12; i++) { float d = v[i] - mean; q += d * d; }
  #pragma unroll
  for (int m = 32; m >= 1; m >>= 1) q += __shfl_xor(q, m);
  float rstd = rsqrtf(q * (1.f / 768.f) + 1e-5f);
  u16* o = out + (size_t)row * Cc;
  #pragma unroll
  for (int i = 0; i < 6; i++) {
    int j = 2 * (lane + i * 64);
    u16 lo = f2bf((v[2 * i]     - mean) * rstd * gam[j]     + bet[j]);
    u16 hi = f2bf((v[2 * i + 1] - mean) * rstd * gam[j + 1] + bet[j + 1]);
    *(u32*)&o[j] = (u32)lo | ((u32)hi << 16);
  }
}

// ---------------- GEMM args (shared by both tile variants) ----------------
struct GemmArgs {
  const u16* A; const u16* W; const float* bias;
  int M, N, K;
  const u16* resBf;     // bf16 residual input (EPI 1 & 3)
  float* outF;
  u16* outBf;
  u16 *q, *k, *v;
};

// ---------------- 256^2 GEMM (r19 schedule) — used for QKV (EPI0), fc1 (EPI2) --
template <int EPI>
__global__ __launch_bounds__(512, 2) void k_gemm(GemmArgs p) {
  extern __shared__ f32x4 smv[];
  u16* lA = (u16*)smv;            // [2][256][64] bf16
  u16* lB = (u16*)smv + 2 * 256 * 64;
  const int tid = threadIdx.x;
  const int wave = tid >> 6, lane = tid & 63;
  const int l15 = lane & 15, g = lane >> 4, h7 = l15 & 7;
  const int wr = wave >> 2, wc = wave & 3;
  const int rl = tid >> 3, cc8 = tid & 7;
  const int nwg = gridDim.x * gridDim.y;
  const int wg = blockIdx.y * gridDim.x + blockIdx.x;
  const int swz = (wg & 7) * (nwg >> 3) + (wg >> 3);
  const int bn = (swz % gridDim.x) * 256, bm = (swz / gridDim.x) * 256;
  const int K = p.K;

  f32x4 acc[8][4];
  #pragma unroll
  for (int i = 0; i < 8; i++)
    #pragma unroll
    for (int j = 0; j < 4; j++) acc[i][j] = (f32x4){0.f, 0.f, 0.f, 0.f};

  const u16* Ab = p.A + (size_t)bm * K;
  const u16* Wb = p.W + (size_t)bn * K;
  const int csw = (cc8 ^ (rl & 7)) * 8;   // source-preswizzled k-chunk

  auto stageA = [&](int buf, int k0, int half) {
    int r0 = half * 64 + rl, r1 = r0 + 128;
    gload16(Ab + (size_t)r0 * K + k0 + csw, &lA[buf * 16384 + r0 * 64 + cc8 * 8]);
    gload16(Ab + (size_t)r1 * K + k0 + csw, &lA[buf * 16384 + r1 * 64 + cc8 * 8]);
  };
  auto stageB = [&](int buf, int k0, int half) {
    int r0 = ((rl >> 5) << 6) + half * 32 + (rl & 31), r1 = r0 + 128;
    gload16(Wb + (size_t)r0 * K + k0 + csw, &lB[buf * 16384 + r0 * 64 + cc8 * 8]);
    gload16(Wb + (size_t)r1 * K + k0 + csw, &lB[buf * 16384 + r1 * 64 + cc8 * 8]);
  };

  bf16x8 a[4][2], bq[4][2];
  auto rdA = [&](int buf, int mt, int kk) {
    int row = wr * 128 + mt * 16 + l15;       // row&7 == h7
    return *(const bf16x8*)&lA[buf * 16384 + row * 64 + (((kk << 2) + g) ^ h7) * 8];
  };
  auto rdB = [&](int buf, int nt, int kk) {
    int row = wc * 64 + nt * 16 + l15;        // row&7 == h7
    return *(const bf16x8*)&lB[buf * 16384 + row * 64 + (((kk << 2) + g) ^ h7) * 8];
  };
  auto MF = [&](auto MBt, auto NBt) {         // 16 MFMAs = one quadrant x K=64
    constexpr int MB = decltype(MBt)::v, NB = decltype(NBt)::v;
    __builtin_amdgcn_s_setprio(1);
    #pragma unroll
    for (int kk = 0; kk < 2; kk++)
      #pragma unroll
      for (int mi = 0; mi < 4; mi++)
        #pragma unroll
        for (int ni = 0; ni < 2; ni++)
          acc[MB + mi][NB + ni] = __builtin_amdgcn_mfma_f32_16x16x32_bf16(
              a[mi][kk], bq[NB + ni][kk], acc[MB + mi][NB + ni], 0, 0, 0);
    __builtin_amdgcn_s_setprio(0);
  };

  // prologue: t0.{ch0..ch3}, t1.ch0 -> 10 loads; wait oldest 4 (t0.ch0,ch1)
  stageA(0, 0, 0); stageB(0, 0, 0); stageB(0, 0, 1); stageA(0, 0, 1);
  stageA(1, 64, 0);
  asm volatile("s_waitcnt vmcnt(6)" ::: "memory");
  __builtin_amdgcn_s_barrier();

  auto TILE = [&](int t, auto tag) {
    constexpr int TAIL = decltype(tag)::v;    // 0 steady, 1 = NT-2, 2 = NT-1
    const int buf = t & 1, nb = buf ^ 1;
    const int k1 = (t + 1) * 64;
    // ph0: A-lo + B-n0 reads; stage B(t+1,half0); guarantee t.ch2
    #pragma unroll
    for (int mi = 0; mi < 4; mi++) { a[mi][0] = rdA(buf, mi, 0); a[mi][1] = rdA(buf, mi, 1); }
    #pragma unroll
    for (int ni = 0; ni < 2; ni++) { bq[ni][0] = rdB(buf, ni, 0); bq[ni][1] = rdB(buf, ni, 1); }
    if constexpr (TAIL < 2) {
      stageB(nb, k1, 0);
      asm volatile("s_waitcnt vmcnt(6)" ::: "memory");
    } else {
      asm volatile("s_waitcnt vmcnt(2)" ::: "memory");
    }
    __builtin_amdgcn_s_barrier();
    __builtin_amdgcn_sched_barrier(0);
    MF(Tag<0>{}, Tag<0>{});
    // ph1: B-n1 reads; stage B(t+1,half1); guarantee t.ch3
    #pragma unroll
    for (int ni = 0; ni < 2; ni++) { bq[2 + ni][0] = rdB(buf, 2 + ni, 0); bq[2 + ni][1] = rdB(buf, 2 + ni, 1); }
    if constexpr (TAIL < 2) {
      stageB(nb, k1, 1);
      asm volatile("s_waitcnt vmcnt(6)" ::: "memory");
    } else {
      asm volatile("s_waitcnt vmcnt(0)" ::: "memory");
    }
    __builtin_amdgcn_s_barrier();
    __builtin_amdgcn_sched_barrier(0);
    MF(Tag<0>{}, Tag<2>{});
    // ph2: A-hi reads; stage A(t+1,half1)
    #pragma unroll
    for (int mi = 0; mi < 4; mi++) { a[mi][0] = rdA(buf, 4 + mi, 0); a[mi][1] = rdA(buf, 4 + mi, 1); }
    if constexpr (TAIL < 2) stageA(nb, k1, 1);
    __builtin_amdgcn_s_barrier();
    __builtin_amdgcn_sched_barrier(0);
    MF(Tag<4>{}, Tag<2>{});
    // ph3: no new ds_reads (bq n0 held); stage A(t+2,half0) into buf
    if constexpr (TAIL == 0) {
      stageA(buf, k1 + 64, 0);
      asm volatile("s_waitcnt vmcnt(6)" ::: "memory");
    } else if constexpr (TAIL == 1) {
      asm volatile("s_waitcnt vmcnt(4)" ::: "memory");
    }
    __builtin_amdgcn_s_barrier();
    __builtin_amdgcn_sched_barrier(0);
    MF(Tag<4>{}, Tag<0>{});
  };

  const int NT = K >> 6;
  for (int t = 0; t < NT - 2; ++t) TILE(t, Tag<0>{});
  TILE(NT - 2, Tag<1>{});
  TILE(NT - 1, Tag<2>{});

  // Epilogue. D layout: col = lane&15, row = (lane>>4)*4 + reg.
  #pragma unroll
  for (int mt = 0; mt < 8; mt++) {
    int rowb = bm + wr * 128 + mt * 16 + g * 4;
    #pragma unroll
    for (int nt = 0; nt < 4; nt++) {
      int col = bn + wc * 64 + nt * 16 + l15;
      float bias = p.bias[col];
      if constexpr (EPI == 0) {        // QKV scatter; q pre-scaled; v transposed
        #pragma unroll
        for (int r = 0; r < 4; r++) {
          int grow = rowb + r;
          int bb = grow >> 10, nnq = grow & 1023;
          float val = acc[mt][nt][r] + bias;
          if (col < 768) {
            int head = col >> 6, d = col & 63;
            p.q[(((size_t)bb * NH + head) * Nn + nnq) * HD + d] = f2bf(val * (0.125f * LOG2E));
          } else {
            int j2 = col - 768;
            if (j2 < 768) {
              int head = j2 >> 6, d = j2 & 63;
              p.k[(((size_t)bb * NH + head) * Nn + nnq) * HD + d] = f2bf(val);
            } else {
              int j3 = j2 - 768;
              int head = j3 >> 6, d = j3 & 63;
              p.v[(((size_t)bb * NH + head) * HD + d) * Nn + nnq] = f2bf(val);
            }
          }
        }
      } else if constexpr (EPI == 2) { // fc1 + GELU (A&S erf) -> bf16
        #pragma unroll
        for (int r = 0; r < 4; r++) {
          float val = acc[mt][nt][r] + bias;
          p.outBf[(size_t)(rowb + r) * p.N + col] = f2bf(gelu_f(val));
        }
      }
    }
  }
}

// ---------------- 128^2 GEMM (proven rounds 0-5) — proj (EPI1), fc2 (EPI3) ----
// 16KB LDS, 256 thr, 4 waves -> grid 768 blocks, ~3 blocks/CU co-resident.
template <int EPI>
__global__ __launch_bounds__(256) void k_gemm128(GemmArgs p) {
  __shared__ __align__(16) u16 lA[128 * 32];   // linear [row][32]
  __shared__ __align__(16) u16 lB[128 * 32];
  const int tid = threadIdx.x;
  const int wave = tid >> 6, lane = tid & 63;
  const int l15 = lane & 15, g = lane >> 4;
  const int wrow = wave >> 1, wcol = wave & 1;
  const int nwg = gridDim.x * gridDim.y;
  const int wg = blockIdx.y * gridDim.x + blockIdx.x;
  const int swz = (wg & 7) * (nwg >> 3) + (wg >> 3);
  const int bn = (swz % gridDim.x) * 128, bm = (swz / gridDim.x) * 128;
  const int K = p.K;
  f32x4 acc[4][4];
  #pragma unroll
  for (int i = 0; i < 4; i++)
    #pragma unroll
    for (int j = 0; j < 4; j++) acc[i][j] = (f32x4){0.f, 0.f, 0.f, 0.f};

  const u16* Ab = p.A + (size_t)bm * K;
  const u16* Wb = p.W + (size_t)bn * K;
  const int c0 = tid, c1 = tid + 256;
  const int r0 = c0 >> 2, k80 = (c0 & 3) * 8;
  const int r1 = c1 >> 2, k81 = (c1 & 3) * 8;

  for (int kt = 0; kt < K; kt += 32) {
    __syncthreads();
    gload16(Ab + (size_t)r0 * K + kt + k80, &lA[c0 * 8]);
    gload16(Ab + (size_t)r1 * K + kt + k81, &lA[c1 * 8]);
    gload16(Wb + (size_t)r0 * K + kt + k80, &lB[c0 * 8]);
    gload16(Wb + (size_t)r1 * K + kt + k81, &lB[c1 * 8]);
    __syncthreads();
    bf16x8 af[4], bfr[4];
    #pragma unroll
    for (int mt = 0; mt < 4; mt++)
      af[mt] = *(const bf16x8*)&lA[(wrow * 64 + mt * 16 + l15) * 32 + g * 8];
    #pragma unroll
    for (int nt = 0; nt < 4; nt++)
      bfr[nt] = *(const bf16x8*)&lB[(wcol * 64 + nt * 16 + l15) * 32 + g * 8];
    __builtin_amdgcn_s_setprio(1);
    #pragma unroll
    for (int mt = 0; mt < 4; mt++)
      #pragma unroll
      for (int nt = 0; nt < 4; nt++)
        acc[mt][nt] = __builtin_amdgcn_mfma_f32_16x16x32_bf16(af[mt], bfr[nt], acc[mt][nt], 0, 0, 0);
    __builtin_amdgcn_s_setprio(0);
  }

  // Epilogue. D layout: col = lane&15, row = (lane>>4)*4 + reg.
  #pragma unroll
  for (int mt = 0; mt < 4; mt++) {
    int rowb = bm + wrow * 64 + mt * 16 + g * 4;
    #pragma unroll
    for (int nt = 0; nt < 4; nt++) {
      int col = bn + wcol * 64 + nt * 16 + l15;
      float bias = p.bias[col];
      if constexpr (EPI == 1) {        // proj + bf16 residual -> bf16 xt2
        #pragma unroll
        for (int r = 0; r < 4; r++) {
          size_t idx = (size_t)(rowb + r) * p.N + col;
          p.outBf[idx] = f2bf(acc[mt][nt][r] + bias + bf2f(p.resBf[idx]));
        }
      } else {                         // fc2 + bf16 residual -> d_out [B,C,N] f32
        int bb = rowb >> 10, n0 = rowb & 1023;
        F4 ov;
        #pragma unroll
        for (int r = 0; r < 4; r++)
          ov.v[r] = acc[mt][nt][r] + bias + bf2f(p.resBf[(size_t)(rowb + r) * Cc + col]);
        *(F4*)&p.outF[((size_t)bb * Cc + col) * Nn + n0] = ov;
      }
    }
  }
}

// ---------------- flash attention: round-14 (3-deep KV pipeline) ----------------
__global__ __launch_bounds__(512, 4) void k_attn(const u16* __restrict__ qt,
    const u16* __restrict__ kt_, const u16* __restrict__ vtt,
    const u16* __restrict__ bias2, u16* __restrict__ o) {
  __shared__ __align__(16) u16 lK[3][64 * 64];
  __shared__ __align__(16) u16 lV[3][64 * 64];
  __shared__ __align__(16) u16 lP[8][16 * 64];
  const int tid = threadIdx.x, wave = tid >> 6, lane = tid & 63;
  const int l15 = lane & 15, g = lane >> 4;
  const int i_ = blockIdx.x;
  const int slot = i_ >> 3;
  const int hx = (i_ & 7) * 12 + (slot >> 4);
  const int b = slot & 15, h = hx >> 3;
  const int q0 = (hx & 7) * 128 + wave * 16;
  const size_t bh  = ((size_t)b * NH + h) * Nn * HD;
  const size_t bhT = ((size_t)b * NH + h) * HD * Nn;
  const u16* biasH = bias2 + (size_t)h * Nn * Nn;
  u16* myP = &lP[wave][0];
  const float THR = 8.f * LOG2E;
  const int sRow = tid >> 3, sCol = tid & 7;
  const int h7 = l15 & 7;

  bf16x8 qa0, qa1;
  {
    const u16* qp = qt + bh + (size_t)(q0 + l15) * HD + g * 8;
    qa0 = *(const bf16x8*)qp;
    qa1 = *(const bf16x8*)(qp + 32);
  }
  bf16x8 ones;
  #pragma unroll
  for (int i = 0; i < 8; i++) ones[i] = (short)0x3F80;

  f32x4 ao[4];
  f32x4 al;
  float mr = -1e30f;
  #pragma unroll
  for (int d = 0; d < 4; d++) ao[d] = (f32x4){0.f, 0.f, 0.f, 0.f};
  al = (f32x4){0.f, 0.f, 0.f, 0.f};

  auto issueKV = [&](int kt0, int buf) {
    int cs = (sCol ^ (sRow & 7)) << 3;
    gload16(kt_ + bh + (size_t)(kt0 + sRow) * HD + cs, &lK[buf][sRow * 64 + sCol * 8]);
    gload16(vtt + bhT + (size_t)sRow * Nn + kt0 + cs, &lV[buf][sRow * 64 + sCol * 8]);
  };

  issueKV(0, 0);
  issueKV(64, 1);
  int buf = 0, nbuf = 2;
  for (int t = 0; t < 16; ++t) {
    if (t < 15) asm volatile("s_waitcnt vmcnt(2) lgkmcnt(0)" ::: "memory");
    else        asm volatile("s_waitcnt vmcnt(0) lgkmcnt(0)" ::: "memory");
    __builtin_amdgcn_s_barrier();
    __builtin_amdgcn_sched_barrier(0);

    us4 bvv[4];
    #pragma unroll
    for (int nt = 0; nt < 4; nt++)
      bvv[nt] = *(const us4*)(biasH + (size_t)(q0 + l15) * Nn + t * 64 + nt * 16 + g * 4);
    __builtin_amdgcn_sched_barrier(0);
    if (t < 14) issueKV((t + 2) * 64, nbuf);
    __builtin_amdgcn_sched_barrier(0);

    f32x4 s[4];
    __builtin_amdgcn_s_setprio(1);
    #pragma unroll
    for (int nt = 0; nt < 4; nt++) {
      const int row = nt * 16 + l15;
      bf16x8 kb0 = *(const bf16x8*)&lK[buf][row * 64 + ((g ^ h7) << 3)];
      bf16x8 kb1 = *(const bf16x8*)&lK[buf][row * 64 + (((g + 4) ^ h7) << 3)];
      s[nt] = __builtin_amdgcn_mfma_f32_16x16x32_bf16(kb0, qa0,
                (f32x4){0.f, 0.f, 0.f, 0.f}, 0, 0, 0);
      s[nt] = __builtin_amdgcn_mfma_f32_16x16x32_bf16(kb1, qa1, s[nt], 0, 0, 0);
    }
    __builtin_amdgcn_s_setprio(0);

    #pragma unroll
    for (int nt = 0; nt < 4; nt++) {
      #pragma unroll
      for (int r = 0; r < 4; r++) s[nt][r] += bf2f(bvv[nt][r]);
    }
    float pm = fmaxf(fmaxf(s[0][0], s[0][1]), fmaxf(s[0][2], s[0][3]));
    #pragma unroll
    for (int nt = 1; nt < 4; nt++)
      pm = fmaxf(pm, fmaxf(fmaxf(s[nt][0], s[nt][1]), fmaxf(s[nt][2], s[nt][3])));
    pm = fmaxf(pm, __shfl_xor(pm, 16));
    pm = fmaxf(pm, __shfl_xor(pm, 32));
    if (__any(pm > mr + THR)) {
      float mnew = fmaxf(mr, pm);
      float fac = __builtin_amdgcn_exp2f(mr - mnew);
      mr = mnew;
      f32x4 facO;
      #pragma unroll
      for (int r = 0; r < 4; r++) facO[r] = __shfl(fac, g * 4 + r);
      #pragma unroll
      for (int d = 0; d < 4; d++) ao[d] *= facO;
      al *= facO;
    }
    #pragma unroll
    for (int nt = 0; nt < 4; nt++) {
      #pragma unroll
      for (int r = 0; r < 4; r++)
        s[nt][r] = __builtin_amdgcn_exp2f(s[nt][r] - mr);
    }
    #pragma unroll
    for (int nt = 0; nt < 4; nt++) {
      u32 w0, w1;
      asm("v_cvt_pk_bf16_f32 %0, %1, %2" : "=v"(w0) : "v"(s[nt][0]), "v"(s[nt][1]));
      asm("v_cvt_pk_bf16_f32 %0, %1, %2" : "=v"(w1) : "v"(s[nt][2]), "v"(s[nt][3]));
      int cbase = (((2 * nt + (g >> 1)) ^ h7) << 3) + (g & 1) * 4;
      *(u32*)&myP[l15 * 64 + cbase]     = w0;
      *(u32*)&myP[l15 * 64 + cbase + 2] = w1;
    }
    __builtin_amdgcn_s_setprio(1);
    #pragma unroll
    for (int kc = 0; kc < 2; kc++) {
      bf16x8 pa = *(const bf16x8*)&myP[l15 * 64 + (((4 * kc + g) ^ h7) << 3)];
      al = __builtin_amdgcn_mfma_f32_16x16x32_bf16(pa, ones, al, 0, 0, 0);
      #pragma unroll
      for (int d = 0; d < 4; d++) {
        const int rv = d * 16 + l15;
        bf16x8 vb = *(const bf16x8*)&lV[buf][rv * 64 + (((kc * 4 + g) ^ h7) << 3)];
        ao[d] = __builtin_amdgcn_mfma_f32_16x16x32_bf16(pa, vb, ao[d], 0, 0, 0);
      }
    }
    __builtin_amdgcn_s_setprio(0);
    buf = (buf == 2) ? 0 : buf + 1;
    nbuf = (nbuf == 2) ? 0 : nbuf + 1;
  }
  f32x4 linv;
  #pragma unroll
  for (int r = 0; r < 4; r++) linv[r] = __builtin_amdgcn_rcpf(al[r]);
  #pragma unroll
  for (int r = 0; r < 4; r++) {
    int qg = q0 + g * 4 + r;
    u16* op = o + ((size_t)b * Nn + qg) * Cc + h * HD;
    #pragma unroll
    for (int d = 0; d < 4; d++)
      op[d * 16 + l15] = f2bf(ao[d][r] * linv[r]);
  }
}

// ---------------- host ----------------
extern "C" void kernel_launch(void* const* d_in, const int* in_sizes, int n_in,
                              void* d_out, int out_size, void* d_ws, size_t ws_size,
                              hipStream_t stream) {
  const float* x      = (const float*)d_in[0];
  const float* rpb    = (const float*)d_in[1];
  const float* g1     = (const float*)d_in[2];
  const float* b1v    = (const float*)d_in[3];
  const float* q_w    = (const float*)d_in[4];
  const float* q_b    = (const float*)d_in[5];
  const float* kv_w   = (const float*)d_in[6];
  const float* kv_b   = (const float*)d_in[7];
  const float* proj_w = (const float*)d_in[8];
  const float* proj_b = (const float*)d_in[9];
  const float* g2     = (const float*)d_in[10];
  const float* b2v    = (const float*)d_in[11];
  const float* fc1_w  = (const float*)d_in[12];
  const float* fc1_b  = (const float*)d_in[13];
  const float* fc2_w  = (const float*)d_in[14];
  const float* fc2_b  = (const float*)d_in[15];
  const int*   rel    = (const int*)d_in[16];
  float* out = (float*)d_out;

  char* ws = (char*)d_ws;
  size_t off = 0;
  auto alloc = [&](size_t bytes) -> void* {
    void* p = ws + off;
    off += (bytes + 255) & ~(size_t)255;
    return p;
  };
  u16*   wqkv  = (u16*)alloc((size_t)2304 * 768 * 2);
  u16*   wproj = (u16*)alloc((size_t)768 * 768 * 2);
  u16*   wfc1  = (u16*)alloc((size_t)3072 * 768 * 2);
  u16*   wfc2  = (u16*)alloc((size_t)768 * 3072 * 2);
  float* bqkv  = (float*)alloc((size_t)2304 * 4);
  u16*   xt    = (u16*)alloc((size_t)16384 * 768 * 2);   // bf16 residual 1
  u16*   xt2   = (u16*)alloc((size_t)16384 * 768 * 2);   // bf16 residual 2
  u16*   xn    = (u16*)alloc((size_t)16384 * 768 * 2);
  u16*   qb_   = (u16*)alloc((size_t)Bb * NH * Nn * HD * 2);
  u16*   kb_   = (u16*)alloc((size_t)Bb * NH * Nn * HD * 2);
  u16*   vb_   = (u16*)alloc((size_t)Bb * NH * Nn * HD * 2);
  u16*   ob_   = (u16*)alloc((size_t)16384 * 768 * 2);
  u16*   h1    = qb_;            // fc1 out aliases q+k+v+o region
  u16*   bias2 = xt2;            // bias2 (25.2MB) aliases xt2 (dead until proj)

  hipFuncSetAttribute((const void*)k_gemm<0>, hipFuncAttributeMaxDynamicSharedMemorySize, 131072);
  hipFuncSetAttribute((const void*)k_gemm<2>, hipFuncAttributeMaxDynamicSharedMemorySize, 131072);

  // merged prep (x4) + transpose + bias_pre (x4): 6913 + 12288 + 12288 = 31489
  k_pre_all<<<31489, 256, 0, stream>>>(q_w, kv_w, proj_w, fc1_w, fc2_w, q_b, kv_b,
                                       wqkv, wproj, wfc1, wfc2, bqkv,
                                       x, xt, rpb, rel, bias2);

  k_layernorm<<<4096, 256, 0, stream>>>(xt, g1, b1v, xn);

  GemmArgs ga = {};
  ga.A = xn; ga.W = wqkv; ga.bias = bqkv; ga.M = 16384; ga.N = 2304; ga.K = 768;
  ga.q = qb_; ga.k = kb_; ga.v = vb_;
  k_gemm<0><<<dim3(9, 64), 512, 131072, stream>>>(ga);

  k_attn<<<1536, 512, 0, stream>>>(qb_, kb_, vb_, bias2, ob_);

  GemmArgs gp = {};
  gp.A = ob_; gp.W = wproj; gp.bias = proj_b; gp.M = 16384; gp.N = 768; gp.K = 768;
  gp.resBf = xt; gp.outBf = xt2;
  k_gemm128<1><<<dim3(6, 128), 256, 0, stream>>>(gp);

  k_layernorm<<<4096, 256, 0, stream>>>(xt2, g2, b2v, xn);

  GemmArgs gf1 = {};
  gf1.A = xn; gf1.W = wfc1; gf1.bias = fc1_b; gf1.M = 16384; gf1.N = 3072; gf1.K = 768;
  gf1.outBf = h1;
  k_gemm<2><<<dim3(12, 64), 512, 131072, stream>>>(gf1);

  GemmArgs gf2 = {};
  gf2.A = h1; gf2.W = wfc2; gf2.bias = fc2_b; gf2.M = 16384; gf2.N = 768; gf2.K = 3072;
  gf2.resBf = xt2; gf2.outF = out;
  k_gemm128<3><<<dim3(6, 128), 256, 0, stream>>>(gf2);
}

// Round 22
// 491.264 us; speedup vs baseline: 1.0187x; 1.0187x over previous
//
// ViT block on MI355X — FINAL: round 19/21/23 banked optimum (491.3/493.7/491.4
// across three runs). Local optimum confirmed on GEMM sync (r20 +barriers = +17,
// r22 -barriers = +14), tile shape (r24 128^2 = +9), attn schedule (4 variants),
// traffic (FETCH at unique-input footprint), epilogues, prep, launch count.
// Session: 606.5 -> 491.3 us (-19.0%).
#include <hip/hip_runtime.h>
#include <hip/hip_bf16.h>
#include <math.h>

typedef unsigned short u16;
typedef unsigned int u32;
typedef float f32x4 __attribute__((ext_vector_type(4)));
typedef short bf16x8 __attribute__((ext_vector_type(8)));
typedef unsigned short us4 __attribute__((ext_vector_type(4)));
typedef int i32x4 __attribute__((ext_vector_type(4)));

struct alignas(16) F4 { float v[4]; };
template <int N> struct Tag { static constexpr int v = N; };

static constexpr int Bb = 16;
static constexpr int Cc = 768;
static constexpr int Nn = 1024;
static constexpr int NH = 12;
static constexpr int HD = 64;
static constexpr float LOG2E = 1.4426950408889634f;

static __device__ __forceinline__ u16 f2bf(float f) {
  union { float f; unsigned u; } v; v.f = f;
  unsigned u = v.u;
  u += 0x7fffu + ((u >> 16) & 1u);
  return (u16)(u >> 16);
}
static __device__ __forceinline__ float bf2f(u16 x) {
  union { unsigned u; float f; } v; v.u = ((unsigned)x) << 16; return v.f;
}
static __device__ __forceinline__ void gload16(const u16* g, u16* l) {
  __builtin_amdgcn_global_load_lds((const __attribute__((address_space(1))) u32*)g,
                                   (__attribute__((address_space(3))) u32*)l, 16, 0, 0);
}
// exact-GELU via A&S 7.1.26 erf (max abs err 1.5e-7 < bf16 ulp of output)
static __device__ __forceinline__ float gelu_f(float v) {
  float z = v * 0.70710678118654752f;
  float az = fabsf(z);
  float t = __builtin_amdgcn_rcpf(1.f + 0.3275911f * az);
  float poly = t * (0.254829592f + t * (-0.284496736f + t * (1.421413741f +
               t * (-1.453152027f + t * 1.061405429f))));
  float e = __builtin_amdgcn_exp2f(-az * az * LOG2E);
  float erfv = 1.f - poly * e;
  erfv = (z < 0.f) ? -erfv : erfv;
  return 0.5f * v * (1.f + erfv);
}
static __device__ __forceinline__ us4 pack4(const float* s) {
  us4 r;
  r[0] = f2bf(s[0]); r[1] = f2bf(s[1]); r[2] = f2bf(s[2]); r[3] = f2bf(s[3]);
  return r;
}

// ---- merged prep (x4 vectorized): weight/bias conversion + x transpose (bf16)
// + attn-bias table. blocks [0,6913): prep4; [6913,19201): transpose;
// [19201,31489): bias_pre4.
__global__ __launch_bounds__(256) void k_pre_all(const float* __restrict__ q_w,
    const float* __restrict__ kv_w, const float* __restrict__ proj_w,
    const float* __restrict__ fc1_w, const float* __restrict__ fc2_w,
    const float* __restrict__ q_b, const float* __restrict__ kv_b,
    u16* __restrict__ wqkv, u16* __restrict__ wproj, u16* __restrict__ wfc1,
    u16* __restrict__ wfc2, float* __restrict__ bqkv,
    const float* __restrict__ x, u16* __restrict__ xt,
    const float* __restrict__ rpb, const int* __restrict__ rel,
    u16* __restrict__ bias2) {
  const int bid = blockIdx.x, tid = threadIdx.x;
  if (bid < 6913) {
    int i4 = bid * 256 + tid;
    if (i4 >= 1769664) return;
    int i = i4 * 4;                       // all segment bounds are %4 == 0
    if (i < 589824) {
      f32x4 sv = *(const f32x4*)&q_w[i];
      *(us4*)&wqkv[i] = pack4((const float*)&sv);
    } else if (i < 1769472) {
      f32x4 sv = *(const f32x4*)&kv_w[i - 589824];
      *(us4*)&wqkv[i] = pack4((const float*)&sv);
    } else if (i < 2359296) {
      f32x4 sv = *(const f32x4*)&proj_w[i - 1769472];
      *(us4*)&wproj[i - 1769472] = pack4((const float*)&sv);
    } else if (i < 4718592) {
      f32x4 sv = *(const f32x4*)&fc1_w[i - 2359296];
      *(us4*)&wfc1[i - 2359296] = pack4((const float*)&sv);
    } else if (i < 7077888) {
      f32x4 sv = *(const f32x4*)&fc2_w[i - 4718592];
      *(us4*)&wfc2[i - 4718592] = pack4((const float*)&sv);
    } else if (i < 7078656) {
      f32x4 sv;
      if (i - 7077888 < 768) sv = *(const f32x4*)&q_b[i - 7077888];
      else                   sv = *(const f32x4*)&kv_b[i - 7078656];
      *(f32x4*)&bqkv[i - 7077888] = sv;
    } else {
      f32x4 sv = *(const f32x4*)&kv_b[i - 7078656];
      *(f32x4*)&bqkv[i - 7077888] = sv;
    }
  } else if (bid < 19201) {
    __shared__ float tile[32][33];
    int j = bid - 6913;
    int n0 = (j & 31) * 32, c0 = ((j >> 5) % 24) * 32, b = j / 768;
    int tx = tid & 31, ty = tid >> 5;   // 32 x 8
    const float* xp = x + (size_t)b * Cc * Nn;
    #pragma unroll
    for (int i = 0; i < 32; i += 8)
      tile[ty + i][tx] = xp[(size_t)(c0 + ty + i) * Nn + n0 + tx];
    __syncthreads();
    u16* xtp = xt + (size_t)b * Nn * Cc;
    #pragma unroll
    for (int i = 0; i < 32; i += 8)
      xtp[(size_t)(n0 + ty + i) * Cc + c0 + tx] = f2bf(tile[tx][ty + i]);
  } else {
    // bias_pre x4: idx over h(12) x q(1024) x kg(256); k = kg*4
    int idx = (bid - 19201) * 256 + tid;
    int kg = idx & 255, q = (idx >> 8) & 1023, h = idx >> 18;
    int k = kg * 4;
    i32x4 rv = *(const i32x4*)&rel[(size_t)q * Nn + k];
    us4 ov;
    ov[0] = f2bf(rpb[rv[0] * NH + h] * LOG2E);
    ov[1] = f2bf(rpb[rv[1] * NH + h] * LOG2E);
    ov[2] = f2bf(rpb[rv[2] * NH + h] * LOG2E);
    ov[3] = f2bf(rpb[rv[3] * NH + h] * LOG2E);
    *(us4*)&bias2[((size_t)h * Nn + q) * Nn + k] = ov;
  }
}

// LayerNorm rows of 768: bf16 in -> bf16 out. One wave/row, 4 rows/block.
__global__ __launch_bounds__(256) void k_layernorm(const u16* __restrict__ in,
    const float* __restrict__ gam, const float* __restrict__ bet,
    u16* __restrict__ out) {
  int wave = threadIdx.x >> 6, lane = threadIdx.x & 63;
  int row = blockIdx.x * 4 + wave;
  const u16* p = in + (size_t)row * Cc;
  float v[12]; float s = 0.f;
  #pragma unroll
  for (int i = 0; i < 6; i++) {
    u32 pr = *(const u32*)&p[2 * (lane + i * 64)];
    v[2 * i]     = bf2f((u16)(pr & 0xffff));
    v[2 * i + 1] = bf2f((u16)(pr >> 16));
    s += v[2 * i] + v[2 * i + 1];
  }
  #pragma unroll
  for (int m = 32; m >= 1; m >>= 1) s += __shfl_xor(s, m);
  float mean = s * (1.f / 768.f);
  float q = 0.f;
  #pragma unroll
  for (int i = 0; i < 12; i++) { float d = v[i] - mean; q += d * d; }
  #pragma unroll
  for (int m = 32; m >= 1; m >>= 1) q += __shfl_xor(q, m);
  float rstd = rsqrtf(q * (1.f / 768.f) + 1e-5f);
  u16* o = out + (size_t)row * Cc;
  #pragma unroll
  for (int i = 0; i < 6; i++) {
    int j = 2 * (lane + i * 64);
    u16 lo = f2bf((v[2 * i]     - mean) * rstd * gam[j]     + bet[j]);
    u16 hi = f2bf((v[2 * i + 1] - mean) * rstd * gam[j + 1] + bet[j + 1]);
    *(u32*)&o[j] = (u32)lo | ((u32)hi << 16);
  }
}

// ---------------- GEMM: C[M,N] = A[M,K] @ W[N,K]^T + bias ----------------
struct GemmArgs {
  const u16* A; const u16* W; const float* bias;
  int M, N, K;
  const u16* resBf;     // bf16 residual input (EPI 1 & 3)
  float* outF;
  u16* outBf;
  u16 *q, *k, *v;
};

template <int EPI>
__global__ __launch_bounds__(512, 2) void k_gemm(GemmArgs p) {
  extern __shared__ f32x4 smv[];
  u16* lA = (u16*)smv;            // [2][256][64] bf16
  u16* lB = (u16*)smv + 2 * 256 * 64;
  const int tid = threadIdx.x;
  const int wave = tid >> 6, lane = tid & 63;
  const int l15 = lane & 15, g = lane >> 4, h7 = l15 & 7;
  const int wr = wave >> 2, wc = wave & 3;
  const int rl = tid >> 3, cc8 = tid & 7;
  const int nwg = gridDim.x * gridDim.y;
  const int wg = blockIdx.y * gridDim.x + blockIdx.x;
  const int swz = (wg & 7) * (nwg >> 3) + (wg >> 3);
  const int bn = (swz % gridDim.x) * 256, bm = (swz / gridDim.x) * 256;
  const int K = p.K;

  f32x4 acc[8][4];
  #pragma unroll
  for (int i = 0; i < 8; i++)
    #pragma unroll
    for (int j = 0; j < 4; j++) acc[i][j] = (f32x4){0.f, 0.f, 0.f, 0.f};

  const u16* Ab = p.A + (size_t)bm * K;
  const u16* Wb = p.W + (size_t)bn * K;
  const int csw = (cc8 ^ (rl & 7)) * 8;   // source-preswizzled k-chunk

  auto stageA = [&](int buf, int k0, int half) {
    int r0 = half * 64 + rl, r1 = r0 + 128;
    gload16(Ab + (size_t)r0 * K + k0 + csw, &lA[buf * 16384 + r0 * 64 + cc8 * 8]);
    gload16(Ab + (size_t)r1 * K + k0 + csw, &lA[buf * 16384 + r1 * 64 + cc8 * 8]);
  };
  auto stageB = [&](int buf, int k0, int half) {
    int r0 = ((rl >> 5) << 6) + half * 32 + (rl & 31), r1 = r0 + 128;
    gload16(Wb + (size_t)r0 * K + k0 + csw, &lB[buf * 16384 + r0 * 64 + cc8 * 8]);
    gload16(Wb + (size_t)r1 * K + k0 + csw, &lB[buf * 16384 + r1 * 64 + cc8 * 8]);
  };

  bf16x8 a[4][2], bq[4][2];
  auto rdA = [&](int buf, int mt, int kk) {
    int row = wr * 128 + mt * 16 + l15;       // row&7 == h7
    return *(const bf16x8*)&lA[buf * 16384 + row * 64 + (((kk << 2) + g) ^ h7) * 8];
  };
  auto rdB = [&](int buf, int nt, int kk) {
    int row = wc * 64 + nt * 16 + l15;        // row&7 == h7
    return *(const bf16x8*)&lB[buf * 16384 + row * 64 + (((kk << 2) + g) ^ h7) * 8];
  };
  auto MF = [&](auto MBt, auto NBt) {         // 16 MFMAs = one quadrant x K=64
    constexpr int MB = decltype(MBt)::v, NB = decltype(NBt)::v;
    __builtin_amdgcn_s_setprio(1);
    #pragma unroll
    for (int kk = 0; kk < 2; kk++)
      #pragma unroll
      for (int mi = 0; mi < 4; mi++)
        #pragma unroll
        for (int ni = 0; ni < 2; ni++)
          acc[MB + mi][NB + ni] = __builtin_amdgcn_mfma_f32_16x16x32_bf16(
              a[mi][kk], bq[NB + ni][kk], acc[MB + mi][NB + ni], 0, 0, 0);
    __builtin_amdgcn_s_setprio(0);
  };

  // prologue: t0.{ch0..ch3}, t1.ch0 -> 10 loads; wait oldest 4 (t0.ch0,ch1)
  stageA(0, 0, 0); stageB(0, 0, 0); stageB(0, 0, 1); stageA(0, 0, 1);
  stageA(1, 64, 0);
  asm volatile("s_waitcnt vmcnt(6)" ::: "memory");
  __builtin_amdgcn_s_barrier();

  auto TILE = [&](int t, auto tag) {
    constexpr int TAIL = decltype(tag)::v;    // 0 steady, 1 = NT-2, 2 = NT-1
    const int buf = t & 1, nb = buf ^ 1;
    const int k1 = (t + 1) * 64;
    // ph0: A-lo + B-n0 reads; stage B(t+1,half0); guarantee t.ch2
    #pragma unroll
    for (int mi = 0; mi < 4; mi++) { a[mi][0] = rdA(buf, mi, 0); a[mi][1] = rdA(buf, mi, 1); }
    #pragma unroll
    for (int ni = 0; ni < 2; ni++) { bq[ni][0] = rdB(buf, ni, 0); bq[ni][1] = rdB(buf, ni, 1); }
    if constexpr (TAIL < 2) {
      stageB(nb, k1, 0);
      asm volatile("s_waitcnt vmcnt(6)" ::: "memory");
    } else {
      asm volatile("s_waitcnt vmcnt(2)" ::: "memory");
    }
    __builtin_amdgcn_s_barrier();
    __builtin_amdgcn_sched_barrier(0);
    MF(Tag<0>{}, Tag<0>{});
    // ph1: B-n1 reads; stage B(t+1,half1); guarantee t.ch3
    #pragma unroll
    for (int ni = 0; ni < 2; ni++) { bq[2 + ni][0] = rdB(buf, 2 + ni, 0); bq[2 + ni][1] = rdB(buf, 2 + ni, 1); }
    if constexpr (TAIL < 2) {
      stageB(nb, k1, 1);
      asm volatile("s_waitcnt vmcnt(6)" ::: "memory");
    } else {
      asm volatile("s_waitcnt vmcnt(0)" ::: "memory");
    }
    __builtin_amdgcn_s_barrier();
    __builtin_amdgcn_sched_barrier(0);
    MF(Tag<0>{}, Tag<2>{});
    // ph2: A-hi reads; stage A(t+1,half1)
    #pragma unroll
    for (int mi = 0; mi < 4; mi++) { a[mi][0] = rdA(buf, 4 + mi, 0); a[mi][1] = rdA(buf, 4 + mi, 1); }
    if constexpr (TAIL < 2) stageA(nb, k1, 1);
    __builtin_amdgcn_s_barrier();
    __builtin_amdgcn_sched_barrier(0);
    MF(Tag<4>{}, Tag<2>{});
    // ph3: no new ds_reads (bq n0 held); stage A(t+2,half0) into buf
    if constexpr (TAIL == 0) {
      stageA(buf, k1 + 64, 0);
      asm volatile("s_waitcnt vmcnt(6)" ::: "memory");
    } else if constexpr (TAIL == 1) {
      asm volatile("s_waitcnt vmcnt(4)" ::: "memory");
    }
    __builtin_amdgcn_s_barrier();
    __builtin_amdgcn_sched_barrier(0);
    MF(Tag<4>{}, Tag<0>{});
  };

  const int NT = K >> 6;
  for (int t = 0; t < NT - 2; ++t) TILE(t, Tag<0>{});
  TILE(NT - 2, Tag<1>{});
  TILE(NT - 1, Tag<2>{});

  // Epilogue. D layout: col = lane&15, row = (lane>>4)*4 + reg.
  #pragma unroll
  for (int mt = 0; mt < 8; mt++) {
    int rowb = bm + wr * 128 + mt * 16 + g * 4;
    #pragma unroll
    for (int nt = 0; nt < 4; nt++) {
      int col = bn + wc * 64 + nt * 16 + l15;
      float bias = p.bias[col];
      if constexpr (EPI == 0) {        // QKV scatter; q pre-scaled; v transposed
        #pragma unroll
        for (int r = 0; r < 4; r++) {
          int grow = rowb + r;
          int bb = grow >> 10, nnq = grow & 1023;
          float val = acc[mt][nt][r] + bias;
          if (col < 768) {
            int head = col >> 6, d = col & 63;
            p.q[(((size_t)bb * NH + head) * Nn + nnq) * HD + d] = f2bf(val * (0.125f * LOG2E));
          } else {
            int j2 = col - 768;
            if (j2 < 768) {
              int head = j2 >> 6, d = j2 & 63;
              p.k[(((size_t)bb * NH + head) * Nn + nnq) * HD + d] = f2bf(val);
            } else {
              int j3 = j2 - 768;
              int head = j3 >> 6, d = j3 & 63;
              p.v[(((size_t)bb * NH + head) * HD + d) * Nn + nnq] = f2bf(val);
            }
          }
        }
      } else if constexpr (EPI == 1) { // proj + bf16 residual -> bf16 xt2
        #pragma unroll
        for (int r = 0; r < 4; r++) {
          size_t idx = (size_t)(rowb + r) * p.N + col;
          p.outBf[idx] = f2bf(acc[mt][nt][r] + bias + bf2f(p.resBf[idx]));
        }
      } else if constexpr (EPI == 2) { // fc1 + GELU (A&S erf) -> bf16
        #pragma unroll
        for (int r = 0; r < 4; r++) {
          float val = acc[mt][nt][r] + bias;
          p.outBf[(size_t)(rowb + r) * p.N + col] = f2bf(gelu_f(val));
        }
      } else {                         // fc2 + bf16 residual -> d_out [B,C,N] f32
        int bb = rowb >> 10, n0 = rowb & 1023;
        F4 ov;
        #pragma unroll
        for (int r = 0; r < 4; r++)
          ov.v[r] = acc[mt][nt][r] + bias + bf2f(p.resBf[(size_t)(rowb + r) * Cc + col]);
        *(F4*)&p.outF[((size_t)bb * Cc + col) * Nn + n0] = ov;
      }
    }
  }
}

// ---------------- flash attention: round-14 (3-deep KV pipeline) ----------------
__global__ __launch_bounds__(512, 4) void k_attn(const u16* __restrict__ qt,
    const u16* __restrict__ kt_, const u16* __restrict__ vtt,
    const u16* __restrict__ bias2, u16* __restrict__ o) {
  __shared__ __align__(16) u16 lK[3][64 * 64];
  __shared__ __align__(16) u16 lV[3][64 * 64];
  __shared__ __align__(16) u16 lP[8][16 * 64];
  const int tid = threadIdx.x, wave = tid >> 6, lane = tid & 63;
  const int l15 = lane & 15, g = lane >> 4;
  const int i_ = blockIdx.x;
  const int slot = i_ >> 3;
  const int hx = (i_ & 7) * 12 + (slot >> 4);
  const int b = slot & 15, h = hx >> 3;
  const int q0 = (hx & 7) * 128 + wave * 16;
  const size_t bh  = ((size_t)b * NH + h) * Nn * HD;
  const size_t bhT = ((size_t)b * NH + h) * HD * Nn;
  const u16* biasH = bias2 + (size_t)h * Nn * Nn;
  u16* myP = &lP[wave][0];
  const float THR = 8.f * LOG2E;
  const int sRow = tid >> 3, sCol = tid & 7;
  const int h7 = l15 & 7;

  bf16x8 qa0, qa1;
  {
    const u16* qp = qt + bh + (size_t)(q0 + l15) * HD + g * 8;
    qa0 = *(const bf16x8*)qp;
    qa1 = *(const bf16x8*)(qp + 32);
  }
  bf16x8 ones;
  #pragma unroll
  for (int i = 0; i < 8; i++) ones[i] = (short)0x3F80;

  f32x4 ao[4];
  f32x4 al;
  float mr = -1e30f;
  #pragma unroll
  for (int d = 0; d < 4; d++) ao[d] = (f32x4){0.f, 0.f, 0.f, 0.f};
  al = (f32x4){0.f, 0.f, 0.f, 0.f};

  auto issueKV = [&](int kt0, int buf) {
    int cs = (sCol ^ (sRow & 7)) << 3;
    gload16(kt_ + bh + (size_t)(kt0 + sRow) * HD + cs, &lK[buf][sRow * 64 + sCol * 8]);
    gload16(vtt + bhT + (size_t)sRow * Nn + kt0 + cs, &lV[buf][sRow * 64 + sCol * 8]);
  };

  issueKV(0, 0);
  issueKV(64, 1);
  int buf = 0, nbuf = 2;
  for (int t = 0; t < 16; ++t) {
    if (t < 15) asm volatile("s_waitcnt vmcnt(2) lgkmcnt(0)" ::: "memory");
    else        asm volatile("s_waitcnt vmcnt(0) lgkmcnt(0)" ::: "memory");
    __builtin_amdgcn_s_barrier();
    __builtin_amdgcn_sched_barrier(0);

    us4 bvv[4];
    #pragma unroll
    for (int nt = 0; nt < 4; nt++)
      bvv[nt] = *(const us4*)(biasH + (size_t)(q0 + l15) * Nn + t * 64 + nt * 16 + g * 4);
    __builtin_amdgcn_sched_barrier(0);
    if (t < 14) issueKV((t + 2) * 64, nbuf);
    __builtin_amdgcn_sched_barrier(0);

    f32x4 s[4];
    __builtin_amdgcn_s_setprio(1);
    #pragma unroll
    for (int nt = 0; nt < 4; nt++) {
      const int row = nt * 16 + l15;
      bf16x8 kb0 = *(const bf16x8*)&lK[buf][row * 64 + ((g ^ h7) << 3)];
      bf16x8 kb1 = *(const bf16x8*)&lK[buf][row * 64 + (((g + 4) ^ h7) << 3)];
      s[nt] = __builtin_amdgcn_mfma_f32_16x16x32_bf16(kb0, qa0,
                (f32x4){0.f, 0.f, 0.f, 0.f}, 0, 0, 0);
      s[nt] = __builtin_amdgcn_mfma_f32_16x16x32_bf16(kb1, qa1, s[nt], 0, 0, 0);
    }
    __builtin_amdgcn_s_setprio(0);

    #pragma unroll
    for (int nt = 0; nt < 4; nt++) {
      #pragma unroll
      for (int r = 0; r < 4; r++) s[nt][r] += bf2f(bvv[nt][r]);
    }
    float pm = fmaxf(fmaxf(s[0][0], s[0][1]), fmaxf(s[0][2], s[0][3]));
    #pragma unroll
    for (int nt = 1; nt < 4; nt++)
      pm = fmaxf(pm, fmaxf(fmaxf(s[nt][0], s[nt][1]), fmaxf(s[nt][2], s[nt][3])));
    pm = fmaxf(pm, __shfl_xor(pm, 16));
    pm = fmaxf(pm, __shfl_xor(pm, 32));
    if (__any(pm > mr + THR)) {
      float mnew = fmaxf(mr, pm);
      float fac = __builtin_amdgcn_exp2f(mr - mnew);
      mr = mnew;
      f32x4 facO;
      #pragma unroll
      for (int r = 0; r < 4; r++) facO[r] = __shfl(fac, g * 4 + r);
      #pragma unroll
      for (int d = 0; d < 4; d++) ao[d] *= facO;
      al *= facO;
    }
    #pragma unroll
    for (int nt = 0; nt < 4; nt++) {
      #pragma unroll
      for (int r = 0; r < 4; r++)
        s[nt][r] = __builtin_amdgcn_exp2f(s[nt][r] - mr);
    }
    #pragma unroll
    for (int nt = 0; nt < 4; nt++) {
      u32 w0, w1;
      asm("v_cvt_pk_bf16_f32 %0, %1, %2" : "=v"(w0) : "v"(s[nt][0]), "v"(s[nt][1]));
      asm("v_cvt_pk_bf16_f32 %0, %1, %2" : "=v"(w1) : "v"(s[nt][2]), "v"(s[nt][3]));
      int cbase = (((2 * nt + (g >> 1)) ^ h7) << 3) + (g & 1) * 4;
      *(u32*)&myP[l15 * 64 + cbase]     = w0;
      *(u32*)&myP[l15 * 64 + cbase + 2] = w1;
    }
    __builtin_amdgcn_s_setprio(1);
    #pragma unroll
    for (int kc = 0; kc < 2; kc++) {
      bf16x8 pa = *(const bf16x8*)&myP[l15 * 64 + (((4 * kc + g) ^ h7) << 3)];
      al = __builtin_amdgcn_mfma_f32_16x16x32_bf16(pa, ones, al, 0, 0, 0);
      #pragma unroll
      for (int d = 0; d < 4; d++) {
        const int rv = d * 16 + l15;
        bf16x8 vb = *(const bf16x8*)&lV[buf][rv * 64 + (((kc * 4 + g) ^ h7) << 3)];
        ao[d] = __builtin_amdgcn_mfma_f32_16x16x32_bf16(pa, vb, ao[d], 0, 0, 0);
      }
    }
    __builtin_amdgcn_s_setprio(0);
    buf = (buf == 2) ? 0 : buf + 1;
    nbuf = (nbuf == 2) ? 0 : nbuf + 1;
  }
  f32x4 linv;
  #pragma unroll
  for (int r = 0; r < 4; r++) linv[r] = __builtin_amdgcn_rcpf(al[r]);
  #pragma unroll
  for (int r = 0; r < 4; r++) {
    int qg = q0 + g * 4 + r;
    u16* op = o + ((size_t)b * Nn + qg) * Cc + h * HD;
    #pragma unroll
    for (int d = 0; d < 4; d++)
      op[d * 16 + l15] = f2bf(ao[d][r] * linv[r]);
  }
}

// ---------------- host ----------------
extern "C" void kernel_launch(void* const* d_in, const int* in_sizes, int n_in,
                              void* d_out, int out_size, void* d_ws, size_t ws_size,
                              hipStream_t stream) {
  const float* x      = (const float*)d_in[0];
  const float* rpb    = (const float*)d_in[1];
  const float* g1     = (const float*)d_in[2];
  const float* b1v    = (const float*)d_in[3];
  const float* q_w    = (const float*)d_in[4];
  const float* q_b    = (const float*)d_in[5];
  const float* kv_w   = (const float*)d_in[6];
  const float* kv_b   = (const float*)d_in[7];
  const float* proj_w = (const float*)d_in[8];
  const float* proj_b = (const float*)d_in[9];
  const float* g2     = (const float*)d_in[10];
  const float* b2v    = (const float*)d_in[11];
  const float* fc1_w  = (const float*)d_in[12];
  const float* fc1_b  = (const float*)d_in[13];
  const float* fc2_w  = (const float*)d_in[14];
  const float* fc2_b  = (const float*)d_in[15];
  const int*   rel    = (const int*)d_in[16];
  float* out = (float*)d_out;

  char* ws = (char*)d_ws;
  size_t off = 0;
  auto alloc = [&](size_t bytes) -> void* {
    void* p = ws + off;
    off += (bytes + 255) & ~(size_t)255;
    return p;
  };
  u16*   wqkv  = (u16*)alloc((size_t)2304 * 768 * 2);
  u16*   wproj = (u16*)alloc((size_t)768 * 768 * 2);
  u16*   wfc1  = (u16*)alloc((size_t)3072 * 768 * 2);
  u16*   wfc2  = (u16*)alloc((size_t)768 * 3072 * 2);
  float* bqkv  = (float*)alloc((size_t)2304 * 4);
  u16*   xt    = (u16*)alloc((size_t)16384 * 768 * 2);   // bf16 residual 1
  u16*   xt2   = (u16*)alloc((size_t)16384 * 768 * 2);   // bf16 residual 2
  u16*   xn    = (u16*)alloc((size_t)16384 * 768 * 2);
  u16*   qb_   = (u16*)alloc((size_t)Bb * NH * Nn * HD * 2);
  u16*   kb_   = (u16*)alloc((size_t)Bb * NH * Nn * HD * 2);
  u16*   vb_   = (u16*)alloc((size_t)Bb * NH * Nn * HD * 2);
  u16*   ob_   = (u16*)alloc((size_t)16384 * 768 * 2);
  u16*   h1    = qb_;            // fc1 out aliases q+k+v+o region
  u16*   bias2 = xt2;            // bias2 (25.2MB) aliases xt2 (dead until proj)

  hipFuncSetAttribute((const void*)k_gemm<0>, hipFuncAttributeMaxDynamicSharedMemorySize, 131072);
  hipFuncSetAttribute((const void*)k_gemm<1>, hipFuncAttributeMaxDynamicSharedMemorySize, 131072);
  hipFuncSetAttribute((const void*)k_gemm<2>, hipFuncAttributeMaxDynamicSharedMemorySize, 131072);
  hipFuncSetAttribute((const void*)k_gemm<3>, hipFuncAttributeMaxDynamicSharedMemorySize, 131072);

  // merged prep (x4) + transpose + bias_pre (x4): 6913 + 12288 + 12288 = 31489
  k_pre_all<<<31489, 256, 0, stream>>>(q_w, kv_w, proj_w, fc1_w, fc2_w, q_b, kv_b,
                                       wqkv, wproj, wfc1, wfc2, bqkv,
                                       x, xt, rpb, rel, bias2);

  k_layernorm<<<4096, 256, 0, stream>>>(xt, g1, b1v, xn);

  GemmArgs ga = {};
  ga.A = xn; ga.W = wqkv; ga.bias = bqkv; ga.M = 16384; ga.N = 2304; ga.K = 768;
  ga.q = qb_; ga.k = kb_; ga.v = vb_;
  k_gemm<0><<<dim3(9, 64), 512, 131072, stream>>>(ga);

  k_attn<<<1536, 512, 0, stream>>>(qb_, kb_, vb_, bias2, ob_);

  GemmArgs gp = {};
  gp.A = ob_; gp.W = wproj; gp.bias = proj_b; gp.M = 16384; gp.N = 768; gp.K = 768;
  gp.resBf = xt; gp.outBf = xt2;
  k_gemm<1><<<dim3(3, 64), 512, 131072, stream>>>(gp);

  k_layernorm<<<4096, 256, 0, stream>>>(xt2, g2, b2v, xn);

  GemmArgs gf1 = {};
  gf1.A = xn; gf1.W = wfc1; gf1.bias = fc1_b; gf1.M = 16384; gf1.N = 3072; gf1.K = 768;
  gf1.outBf = h1;
  k_gemm<2><<<dim3(12, 64), 512, 131072, stream>>>(gf1);

  GemmArgs gf2 = {};
  gf2.A = h1; gf2.W = wfc2; gf2.bias = fc2_b; gf2.M = 16384; gf2.N = 768; gf2.K = 3072;
  gf2.resBf = xt2; gf2.outF = out;
  k_gemm<3><<<dim3(3, 64), 512, 131072, stream>>>(gf2);
}